// Round 20
// baseline (30.129 us; speedup 1.0000x reference)
//
#include <hip/hip_runtime.h>

typedef __attribute__((ext_vector_type(8)))  short short8;
typedef __attribute__((ext_vector_type(16))) float f32x16;
typedef __attribute__((ext_vector_type(16))) unsigned u32x16;

#define NPTS 2048
#define BATCH 32
#define NUM_CLASSES 6
#define THREADS 256
// grid = 32 batches * 8 inst-chunks * 2 model-chunks = 512 blocks
#define BF16_ONE ((short)0x3F80)
#define FMAX_BITS 0x7F7FFFFFu

// ws layout (uint elems): rowmin[32][2048] at 0, colmin[32][2048] at 65536,
// partial[64] floats at 131072. rowmin/colmin pre-set to 0x7F7F7F7F by memset.
#define COL_OFF  65536
#define PART_OFF 131072

__device__ __forceinline__ unsigned short f2bf(float x) {
    union { float f; unsigned u; } v; v.f = x;
    unsigned r = v.u + 0x7FFF + ((v.u >> 16) & 1);   // RNE to bf16
    return (unsigned short)(r >> 16);
}
__device__ __forceinline__ float bf2f(unsigned short h) {
    union { unsigned u; float f; } v; v.u = ((unsigned)h) << 16; return v.f;
}
__device__ __forceinline__ unsigned f2u(float x) {
    union { float f; unsigned u; } v; v.f = x; return v.u;
}
__device__ __forceinline__ float u2f(unsigned x) {
    union { unsigned u; float f; } v; v.u = x; return v.f;
}
// Distances strictly positive -> uint order == float order. umin chains match
// v_min3_u32; atomicMin(uint) is order-independent => deterministic.
__device__ __forceinline__ unsigned umin2(unsigned a, unsigned b) {
    return a < b ? a : b;
}
template<int CTRL>
__device__ __forceinline__ unsigned dpp_ror_umin(unsigned v) {
    unsigned r = (unsigned)__builtin_amdgcn_update_dpp((int)v, (int)v, CTRL, 0xF, 0xF, false);
    return umin2(v, r);
}
__device__ __forceinline__ unsigned swz16_umin(unsigned v) {
    unsigned r = (unsigned)__builtin_amdgcn_ds_swizzle((int)v, 0x401F);  // lane^16
    return umin2(v, r);
}

// K-slot plan (K=16), D = a2 + b2 - 2 a.b (absmax-0 verified R3-R19):
//  k0-2: A=ah B=-2bh | k3-5: A=al B=-2bh | k6-8: A=ah B=-2bl
//  k9: A=1 B=b2h | k10: A=1 B=b2l | k11: A=a2h B=1 | k12: A=a2l B=1 | k13-15: 0
// LDS: per 32-cand tile, 1024 B = [32 x kg0][32 x kg1], conflict-free (R13).
// __launch_bounds__(256,2): 256-VGPR mode (R15). 2-deep pipeline (R18).
// SYMMETRIC: one pass computes d once; row-mins -> dist1, col-mins -> dist2
// via deterministic atomicMin (halves MFMA + staging vs R19's two-dir scheme).
__global__ __launch_bounds__(THREADS, 2) void chamfer_sym(
    const float* __restrict__ inst, const float* __restrict__ model,
    unsigned* __restrict__ ws)
{
    __shared__ char cands[1024 * 32];   // 32 KB (model chunk of 1024)

    const int blk   = blockIdx.x;
    const int mc    = blk & 1;
    const int qc    = (blk >> 1) & 7;
    const int batch = blk >> 4;
    const int tid   = threadIdx.x;
    const int lane  = tid & 63, wid = tid >> 6;
    const int lh    = lane >> 5, lr = lane & 31;

    unsigned* rowmin = ws + batch * NPTS;
    unsigned* colmin = ws + COL_OFF + batch * NPTS + mc * 1024;

    // ---- stage 1024 model cands into tiled B-frag layout (4 per thread) ----
    const float* cb = model + ((size_t)batch * NPTS + (size_t)mc * 1024) * 3;
    #pragma unroll
    for (int k = 0; k < 4; ++k) {
        const int c = tid + k * THREADS;
        float bx = cb[c*3+0], by = cb[c*3+1], bz = cb[c*3+2];
        float m2x = -2.f*bx, m2y = -2.f*by, m2z = -2.f*bz;
        unsigned short hx = f2bf(m2x), hy = f2bf(m2y), hz = f2bf(m2z);
        unsigned short lx = f2bf(m2x - bf2f(hx));
        unsigned short ly = f2bf(m2y - bf2f(hy));
        unsigned short lz = f2bf(m2z - bf2f(hz));
        float b2 = fmaf(bx,bx, fmaf(by,by, bz*bz));
        unsigned short b2h = f2bf(b2);
        unsigned short b2l = f2bf(b2 - bf2f(b2h));
        short8 kg0 = { (short)hx,(short)hy,(short)hz,(short)hx,(short)hy,(short)hz,(short)lx,(short)ly };
        short8 kg1 = { (short)lz,(short)b2h,(short)b2l, BF16_ONE, BF16_ONE, 0,0,0 };
        char* tbase = cands + (c >> 5) * 1024 + (c & 31) * 16;
        *(short8*)(tbase)       = kg0;
        *(short8*)(tbase + 512) = kg1;
    }

    // ---- A-frags: 64 inst rows per wave ----
    short8 af0, af1;
    const float* qb = inst + ((size_t)batch * NPTS + (size_t)qc * 256) * 3;
    #pragma unroll
    for (int qt = 0; qt < 2; ++qt) {
        const int qi = (wid * 2 + qt) * 32 + lr;
        float x = qb[qi*3+0], y = qb[qi*3+1], z = qb[qi*3+2];
        unsigned short hx = f2bf(x), hy = f2bf(y), hz = f2bf(z);
        unsigned short lx = f2bf(x - bf2f(hx));
        unsigned short ly = f2bf(y - bf2f(hy));
        unsigned short lz = f2bf(z - bf2f(hz));
        float a2 = fmaf(x,x, fmaf(y,y, z*z));
        unsigned short a2h = f2bf(a2);
        unsigned short a2l = f2bf(a2 - bf2f(a2h));
        short8 f;
        if (lh == 0)
            f = (short8){ (short)hx,(short)hy,(short)hz,(short)lx,(short)ly,(short)lz,(short)hx,(short)hy };
        else
            f = (short8){ (short)hz, BF16_ONE, BF16_ONE, (short)a2h,(short)a2l, 0,0,0 };
        if (qt == 0) af0 = f; else af1 = f;
    }
    __syncthreads();

    // ---- pipelined loop: 16 stages x 2 tiles; fold stage s-1 (rows + cols) ----
    u32x16 mnU, mnU2;
    f32x16 zero16;
    #pragma unroll
    for (int r = 0; r < 16; ++r) { mnU[r] = FMAX_BITS; mnU2[r] = FMAX_BITS; zero16[r] = 0.f; }

    // FOLD stage results P00=af0*t0, P01=af0*t1, P10=af1*t0, P11=af1*t1;
    // TB = col offset (elems) of tile t0 within this model chunk.
#define FOLD(P00,P01,P10,P11, TB) do {                                         \
    _Pragma("unroll") for (int r = 0; r < 16; ++r)                             \
        mnU[r]  = umin2(umin2(f2u(P00[r]), f2u(P01[r])), mnU[r]);              \
    _Pragma("unroll") for (int r = 0; r < 16; ++r)                             \
        mnU2[r] = umin2(umin2(f2u(P10[r]), f2u(P11[r])), mnU2[r]);             \
    unsigned ca = umin2(f2u(P00[0]), f2u(P10[0]));                             \
    unsigned cc = umin2(f2u(P01[0]), f2u(P11[0]));                             \
    _Pragma("unroll") for (int r = 1; r < 16; ++r) {                           \
        ca = umin2(ca, umin2(f2u(P00[r]), f2u(P10[r])));                       \
        cc = umin2(cc, umin2(f2u(P01[r]), f2u(P11[r])));                       \
    }                                                                          \
    ca = umin2(ca, (unsigned)__shfl_xor((int)ca, 32, 64));                     \
    cc = umin2(cc, (unsigned)__shfl_xor((int)cc, 32, 64));                     \
    if (lh == 0) {                                                             \
        atomicMin(&colmin[(TB) + lr], ca);                                     \
        atomicMin(&colmin[(TB) + 32 + lr], cc);                                \
    }                                                                          \
} while (0)

    const char* cp = cands + lh * 512 + lr * 16;
    short8 c0 = *(const short8*)(cp);
    short8 c1 = *(const short8*)(cp + 1024);
    short8 n0 = *(const short8*)(cp + 2048);
    short8 n1 = *(const short8*)(cp + 3072);
    cp += 4096;
    f32x16 p00 = __builtin_amdgcn_mfma_f32_32x32x16_bf16(af0, c0, zero16, 0,0,0);
    f32x16 p01 = __builtin_amdgcn_mfma_f32_32x32x16_bf16(af0, c1, zero16, 0,0,0);
    f32x16 p10 = __builtin_amdgcn_mfma_f32_32x32x16_bf16(af1, c0, zero16, 0,0,0);
    f32x16 p11 = __builtin_amdgcn_mfma_f32_32x32x16_bf16(af1, c1, zero16, 0,0,0);

    #pragma unroll 2
    for (int s = 1; s < 15; ++s) {        // stages 1..14; folds stages 0..13
        c0 = n0; c1 = n1;
        n0 = *(const short8*)(cp);        // prefetch stage s+1
        n1 = *(const short8*)(cp + 1024);
        cp += 2048;
        f32x16 q00 = __builtin_amdgcn_mfma_f32_32x32x16_bf16(af0, c0, zero16, 0,0,0);
        f32x16 q01 = __builtin_amdgcn_mfma_f32_32x32x16_bf16(af0, c1, zero16, 0,0,0);
        f32x16 q10 = __builtin_amdgcn_mfma_f32_32x32x16_bf16(af1, c0, zero16, 0,0,0);
        f32x16 q11 = __builtin_amdgcn_mfma_f32_32x32x16_bf16(af1, c1, zero16, 0,0,0);
        FOLD(p00, p01, p10, p11, (s - 1) * 64);
        p00 = q00; p01 = q01; p10 = q10; p11 = q11;
    }
    {   // stage 15 (tiles 30,31 prefetched in n0/n1) + drain folds
        f32x16 q00 = __builtin_amdgcn_mfma_f32_32x32x16_bf16(af0, n0, zero16, 0,0,0);
        f32x16 q01 = __builtin_amdgcn_mfma_f32_32x32x16_bf16(af0, n1, zero16, 0,0,0);
        f32x16 q10 = __builtin_amdgcn_mfma_f32_32x32x16_bf16(af1, n0, zero16, 0,0,0);
        f32x16 q11 = __builtin_amdgcn_mfma_f32_32x32x16_bf16(af1, n1, zero16, 0,0,0);
        FOLD(p00, p01, p10, p11, 14 * 64);
        FOLD(q00, q01, q10, q11, 15 * 64);
    }
#undef FOLD

    // ---- row epilogue: DPP col-reduce (R19) -> atomicMin into rowmin ----
    #pragma unroll
    for (int r = 0; r < 16; ++r) {
        const int crow = (r & 3) + 8 * (r >> 2) + 4 * lh;
        unsigned v = mnU[r];
        v = dpp_ror_umin<0x121>(v);
        v = dpp_ror_umin<0x122>(v);
        v = dpp_ror_umin<0x124>(v);
        v = dpp_ror_umin<0x128>(v);
        v = swz16_umin(v);
        if (lr == 0) atomicMin(&rowmin[qc*256 + (wid*2+0)*32 + crow], v);
        unsigned w = mnU2[r];
        w = dpp_ror_umin<0x121>(w);
        w = dpp_ror_umin<0x122>(w);
        w = dpp_ror_umin<0x124>(w);
        w = dpp_ror_umin<0x128>(w);
        w = swz16_umin(w);
        if (lr == 0) atomicMin(&rowmin[qc*256 + (wid*2+1)*32 + crow], w);
    }
}

// ---- kernel 2: 64 blocks, each sums 2048 mins -> partial[64] ---------------
__global__ __launch_bounds__(256) void reduce_kernel(
    const unsigned* __restrict__ ws, float* __restrict__ partial)
{
    const int b   = blockIdx.x;     // 0..63 (rowmin batches 0-31, colmin 32-63)
    const int tid = threadIdx.x;
    const unsigned* base = ws + (size_t)b * NPTS;
    float s = 0.f;
    #pragma unroll
    for (int k = 0; k < 8; ++k) s += u2f(base[k * 256 + tid]);
    #pragma unroll
    for (int o = 32; o > 0; o >>= 1) s += __shfl_down(s, o, 64);
    __shared__ float wsum[4];
    const int lane = tid & 63, wid = tid >> 6;
    if (lane == 0) wsum[wid] = s;
    __syncthreads();
    if (tid == 0) partial[b] = (wsum[0] + wsum[1]) + (wsum[2] + wsum[3]);
}

// ---- kernel 3: 64-sum + cross-entropy + output -----------------------------
__global__ __launch_bounds__(64) void finalize_kernel(
    const float* __restrict__ partial, const float* __restrict__ pred,
    const int* __restrict__ gt, float* __restrict__ out)
{
    const int tid = threadIdx.x;
    __shared__ float s_ce[BATCH];

    float v = partial[tid];
    #pragma unroll
    for (int o = 32; o > 0; o >>= 1) v += __shfl_down(v, o, 64);

    if (tid < BATCH) {
        const float* row = pred + tid * NUM_CLASSES;
        float mx = row[0];
        #pragma unroll
        for (int c = 1; c < NUM_CLASSES; ++c) mx = fmaxf(mx, row[c]);
        float se = 0.f;
        #pragma unroll
        for (int c = 0; c < NUM_CLASSES; ++c) se += __expf(row[c] - mx);
        const int lbl = gt[tid];
        s_ce[tid] = -(row[lbl] - mx - __logf(se));
    }
    __syncthreads();

    if (tid == 0) {
        float cd = v / (float)(BATCH * NPTS);   // (sum rowmin + sum colmin)/65536
        float ce = 0.f;
        for (int i = 0; i < BATCH; ++i) ce += s_ce[i];
        ce /= (float)BATCH;
        out[0] = 5.f * cd + ce;
        out[1] = cd;
        out[2] = ce;
    }
}

extern "C" void kernel_launch(void* const* d_in, const int* in_sizes, int n_in,
                              void* d_out, int out_size, void* d_ws, size_t ws_size,
                              hipStream_t stream) {
    const float* inst  = (const float*)d_in[0];
    const float* model = (const float*)d_in[1];
    const float* pred  = (const float*)d_in[2];
    const int*   gt    = (const int*)d_in[3];
    float* out = (float*)d_out;
    unsigned* ws = (unsigned*)d_ws;

    // init rowmin+colmin to 0x7F7F7F7F (large positive float; > any distance)
    hipMemsetAsync(d_ws, 0x7F, (size_t)PART_OFF * sizeof(unsigned), stream);
    chamfer_sym<<<512, THREADS, 0, stream>>>(inst, model, ws);
    reduce_kernel<<<64, 256, 0, stream>>>(ws, (float*)(ws + PART_OFF));
    finalize_kernel<<<1, 64, 0, stream>>>((float*)(ws + PART_OFF), pred, gt, out);
}

// Round 21
// 27.115 us; speedup vs baseline: 1.1112x; 1.1112x over previous
//
#include <hip/hip_runtime.h>

typedef __attribute__((ext_vector_type(8)))  short short8;
typedef __attribute__((ext_vector_type(16))) float f32x16;
typedef __attribute__((ext_vector_type(16))) unsigned u32x16;

#define NPTS 2048
#define BATCH 32
#define NUM_CLASSES 6
#define THREADS 256
// pass1 grid = 2 dirs * 32 batches * 8 qchunks = 512 blocks
#define BF16_ONE ((short)0x3F80)
#define FMAX_BITS 0x7F7FFFFFu

// ws layout (bytes): bimg[64][2048][32] = 4 MB, then partial[512] floats
#define BIMG_BYTES (64u * 2048u * 32u)

__device__ __forceinline__ unsigned short f2bf(float x) {
    union { float f; unsigned u; } v; v.f = x;
    unsigned r = v.u + 0x7FFF + ((v.u >> 16) & 1);   // RNE to bf16
    return (unsigned short)(r >> 16);
}
__device__ __forceinline__ float bf2f(unsigned short h) {
    union { unsigned u; float f; } v; v.u = ((unsigned)h) << 16; return v.f;
}
__device__ __forceinline__ unsigned f2u(float x) {
    union { float f; unsigned u; } v; v.f = x; return v.u;
}
__device__ __forceinline__ float u2f(unsigned x) {
    union { unsigned u; float f; } v; v.u = x; return v.f;
}
// Distances strictly positive -> uint order == float order (R15-verified).
__device__ __forceinline__ unsigned umin2(unsigned a, unsigned b) {
    return a < b ? a : b;
}
template<int CTRL>
__device__ __forceinline__ unsigned dpp_ror_umin(unsigned v) {
    unsigned r = (unsigned)__builtin_amdgcn_update_dpp((int)v, (int)v, CTRL, 0xF, 0xF, false);
    return umin2(v, r);
}
__device__ __forceinline__ unsigned swz16_umin(unsigned v) {
    unsigned r = (unsigned)__builtin_amdgcn_ds_swizzle((int)v, 0x401F);  // lane^16
    return umin2(v, r);
}
__device__ __forceinline__ void gload_lds16(const char* g, char* l) {
    __builtin_amdgcn_global_load_lds(
        (__attribute__((address_space(1))) void*)(g),
        (__attribute__((address_space(3))) void*)(l), 16, 0, 0);
}

// ---- kernel 0: one-time B-frag conversion (R10 idea, now with clean loop) --
// K-slot plan (K=16), D = a2 + b2 - 2 a.b (absmax-0 verified R3-R19):
//  k0-2: A=ah B=-2bh | k3-5: A=al B=-2bh | k6-8: A=ah B=-2bl
//  k9: A=1 B=b2h | k10: A=1 B=b2l | k11: A=a2h B=1 | k12: A=a2l B=1 | k13-15: 0
// Tiled layout: per 32-cand tile, 1024 B = [32 x kg0][32 x kg1].
__global__ __launch_bounds__(256) void prep_kernel(
    const float* __restrict__ inst, const float* __restrict__ model,
    char* __restrict__ bimg)
{
    const int idx      = blockIdx.x * 256 + threadIdx.x;   // 0..131071
    const int dirbatch = idx >> 11;                        // 0..63
    const int c        = idx & 2047;
    const int dir      = dirbatch >> 5;
    const int batch    = dirbatch & 31;

    // B-side: dir0 = model, dir1 = inst (matches R19's C = dir ? inst : model)
    const float* src = (dir ? inst : model) + ((size_t)batch * NPTS + c) * 3;
    float bx = src[0], by = src[1], bz = src[2];
    float m2x = -2.f*bx, m2y = -2.f*by, m2z = -2.f*bz;
    unsigned short hx = f2bf(m2x), hy = f2bf(m2y), hz = f2bf(m2z);
    unsigned short lx = f2bf(m2x - bf2f(hx));
    unsigned short ly = f2bf(m2y - bf2f(hy));
    unsigned short lz = f2bf(m2z - bf2f(hz));
    float b2 = fmaf(bx,bx, fmaf(by,by, bz*bz));
    unsigned short b2h = f2bf(b2);
    unsigned short b2l = f2bf(b2 - bf2f(b2h));
    short8 kg0 = { (short)hx,(short)hy,(short)hz,(short)hx,(short)hy,(short)hz,(short)lx,(short)ly };
    short8 kg1 = { (short)lz,(short)b2h,(short)b2l, BF16_ONE, BF16_ONE, 0,0,0 };
    char* dst = bimg + (size_t)dirbatch * 65536 + (c >> 5) * 1024 + (c & 31) * 16;
    *(short8*)(dst)       = kg0;
    *(short8*)(dst + 512) = kg1;
}

// ---- kernel 1: MFMA chamfer (R19 loop/epilogue, async preformatted staging) -
__global__ __launch_bounds__(THREADS, 2) void chamfer_mfma32(
    const float* __restrict__ inst, const float* __restrict__ model,
    const char* __restrict__ bimg, float* __restrict__ partial)
{
    __shared__ char  cands[NPTS * 32];   // 64 KB
    __shared__ float wsum[4];

    const int blk   = blockIdx.x;
    const int dir   = blk >> 8;
    const int batch = (blk >> 3) & 31;
    const int qc    = blk & 7;
    const int tid   = threadIdx.x;
    const int lane  = tid & 63, wid = tid >> 6;
    const int lh    = lane >> 5, lr = lane & 31;
    const int dirbatch = dir * BATCH + batch;

    // ---- async stage 64 KB preformatted B-frags: 16 gload_lds/wave, 0 VALU ----
    {
        const char* g = bimg + (size_t)dirbatch * 65536 + wid * 16384 + lane * 16;
        char* l = cands + wid * 16384;       // wave-uniform dest + lane*16
        #pragma unroll
        for (int j = 0; j < 16; ++j)
            gload_lds16(g + j * 1024, l + j * 1024);
    }

    // ---- A-frags from global (row = lane&31, k = (lane>>5)*8 + j) ----
    const float* __restrict__ Q = dir ? model : inst;
    short8 af0, af1;
    const float* qb = Q + ((size_t)batch * NPTS + (size_t)qc * 256) * 3;
    #pragma unroll
    for (int qt = 0; qt < 2; ++qt) {
        const int qi = (wid * 2 + qt) * 32 + lr;
        float x = qb[qi*3+0], y = qb[qi*3+1], z = qb[qi*3+2];
        unsigned short hx = f2bf(x), hy = f2bf(y), hz = f2bf(z);
        unsigned short lx = f2bf(x - bf2f(hx));
        unsigned short ly = f2bf(y - bf2f(hy));
        unsigned short lz = f2bf(z - bf2f(hz));
        float a2 = fmaf(x,x, fmaf(y,y, z*z));
        unsigned short a2h = f2bf(a2);
        unsigned short a2l = f2bf(a2 - bf2f(a2h));
        short8 f;
        if (lh == 0)
            f = (short8){ (short)hx,(short)hy,(short)hz,(short)lx,(short)ly,(short)lz,(short)hx,(short)hy };
        else
            f = (short8){ (short)hz, BF16_ONE, BF16_ONE, (short)a2h,(short)a2l, 0,0,0 };
        if (qt == 0) af0 = f; else af1 = f;
    }
    __syncthreads();   // drains vmcnt -> LDS ready

    // ---- software-pipelined main loop: 32 stages of 2 tiles (R18-verified) ----
    u32x16 mnU, mnU2;
    f32x16 zero16;
    #pragma unroll
    for (int r = 0; r < 16; ++r) { mnU[r] = FMAX_BITS; mnU2[r] = FMAX_BITS; zero16[r] = 0.f; }

    const char* cp = cands + lh * 512 + lr * 16;
    short8 c0 = *(const short8*)(cp);
    short8 c1 = *(const short8*)(cp + 1024);
    short8 n0 = *(const short8*)(cp + 2048);
    short8 n1 = *(const short8*)(cp + 3072);
    cp += 4096;
    f32x16 p00 = __builtin_amdgcn_mfma_f32_32x32x16_bf16(af0, c0, zero16, 0,0,0);
    f32x16 p01 = __builtin_amdgcn_mfma_f32_32x32x16_bf16(af0, c1, zero16, 0,0,0);
    f32x16 p10 = __builtin_amdgcn_mfma_f32_32x32x16_bf16(af1, c0, zero16, 0,0,0);
    f32x16 p11 = __builtin_amdgcn_mfma_f32_32x32x16_bf16(af1, c1, zero16, 0,0,0);

    #pragma unroll 2
    for (int s = 1; s < 31; ++s) {        // stages 1..30 (tiles 2..61)
        c0 = n0; c1 = n1;
        n0 = *(const short8*)(cp);        // prefetch stage s+1
        n1 = *(const short8*)(cp + 1024);
        cp += 2048;
        f32x16 q00 = __builtin_amdgcn_mfma_f32_32x32x16_bf16(af0, c0, zero16, 0,0,0);
        f32x16 q01 = __builtin_amdgcn_mfma_f32_32x32x16_bf16(af0, c1, zero16, 0,0,0);
        f32x16 q10 = __builtin_amdgcn_mfma_f32_32x32x16_bf16(af1, c0, zero16, 0,0,0);
        f32x16 q11 = __builtin_amdgcn_mfma_f32_32x32x16_bf16(af1, c1, zero16, 0,0,0);
        #pragma unroll
        for (int r = 0; r < 16; ++r)      // fold stage s-1 (completed)
            mnU[r]  = umin2(umin2(f2u(p00[r]), f2u(p01[r])), mnU[r]);
        #pragma unroll
        for (int r = 0; r < 16; ++r)
            mnU2[r] = umin2(umin2(f2u(p10[r]), f2u(p11[r])), mnU2[r]);
        p00 = q00; p01 = q01; p10 = q10; p11 = q11;
    }
    {   // stage 31 (tiles 62,63, prefetched in n0/n1) + drain folds
        f32x16 q00 = __builtin_amdgcn_mfma_f32_32x32x16_bf16(af0, n0, zero16, 0,0,0);
        f32x16 q01 = __builtin_amdgcn_mfma_f32_32x32x16_bf16(af0, n1, zero16, 0,0,0);
        f32x16 q10 = __builtin_amdgcn_mfma_f32_32x32x16_bf16(af1, n0, zero16, 0,0,0);
        f32x16 q11 = __builtin_amdgcn_mfma_f32_32x32x16_bf16(af1, n1, zero16, 0,0,0);
        #pragma unroll
        for (int r = 0; r < 16; ++r) {
            mnU[r]  = umin2(umin2(f2u(p00[r]), f2u(p01[r])), mnU[r]);
            mnU2[r] = umin2(umin2(f2u(p10[r]), f2u(p11[r])), mnU2[r]);
        }
        #pragma unroll
        for (int r = 0; r < 16; ++r) {
            mnU[r]  = umin2(umin2(f2u(q00[r]), f2u(q01[r])), mnU[r]);
            mnU2[r] = umin2(umin2(f2u(q10[r]), f2u(q11[r])), mnU2[r]);
        }
    }

    // ---- epilogue: DPP row_ror col-reduce (R19-verified) ----
    float s = 0.f;
    #pragma unroll
    for (int r = 0; r < 16; ++r) {
        unsigned v = mnU[r];
        v = dpp_ror_umin<0x121>(v);
        v = dpp_ror_umin<0x122>(v);
        v = dpp_ror_umin<0x124>(v);
        v = dpp_ror_umin<0x128>(v);
        v = swz16_umin(v);
        s += u2f(v);
        unsigned w = mnU2[r];
        w = dpp_ror_umin<0x121>(w);
        w = dpp_ror_umin<0x122>(w);
        w = dpp_ror_umin<0x124>(w);
        w = dpp_ror_umin<0x128>(w);
        w = swz16_umin(w);
        s += u2f(w);
    }
    s += __shfl_xor(s, 32, 64);      // combine lh=0 / lh=1 query halves
    if (lane == 0) wsum[wid] = s;
    __syncthreads();
    if (tid == 0) partial[blk] = (wsum[0] + wsum[1]) + (wsum[2] + wsum[3]);
}

__global__ __launch_bounds__(256) void finalize_kernel(
    const float* __restrict__ partial, const float* __restrict__ pred,
    const int* __restrict__ gt, float* __restrict__ out)
{
    __shared__ float s_ce[BATCH];
    __shared__ float wsum[4];
    const int tid = threadIdx.x;

    float v = partial[tid] + partial[tid + 256];
    #pragma unroll
    for (int o = 32; o > 0; o >>= 1) v += __shfl_down(v, o, 64);
    const int lane = tid & 63, wid = tid >> 6;
    if (lane == 0) wsum[wid] = v;

    if (tid < BATCH) {
        const float* row = pred + tid * NUM_CLASSES;
        float mx = row[0];
        #pragma unroll
        for (int c = 1; c < NUM_CLASSES; ++c) mx = fmaxf(mx, row[c]);
        float se = 0.f;
        #pragma unroll
        for (int c = 0; c < NUM_CLASSES; ++c) se += __expf(row[c] - mx);
        const int lbl = gt[tid];
        s_ce[tid] = -(row[lbl] - mx - __logf(se));
    }
    __syncthreads();

    if (tid == 0) {
        float cd_sum = (wsum[0] + wsum[1]) + (wsum[2] + wsum[3]);
        float cd = cd_sum / (float)(BATCH * NPTS);
        float ce = 0.f;
        for (int i = 0; i < BATCH; ++i) ce += s_ce[i];
        ce /= (float)BATCH;
        out[0] = 5.f * cd + ce;
        out[1] = cd;
        out[2] = ce;
    }
}

extern "C" void kernel_launch(void* const* d_in, const int* in_sizes, int n_in,
                              void* d_out, int out_size, void* d_ws, size_t ws_size,
                              hipStream_t stream) {
    const float* inst  = (const float*)d_in[0];
    const float* model = (const float*)d_in[1];
    const float* pred  = (const float*)d_in[2];
    const int*   gt    = (const int*)d_in[3];
    float* out  = (float*)d_out;
    char*  bimg = (char*)d_ws;
    float* partial = (float*)((char*)d_ws + BIMG_BYTES);   // 512 floats

    prep_kernel<<<512, 256, 0, stream>>>(inst, model, bimg);
    chamfer_mfma32<<<512, THREADS, 0, stream>>>(inst, model, bimg, partial);
    finalize_kernel<<<1, 256, 0, stream>>>(partial, pred, gt, out);
}

// Round 22
// 17.184 us; speedup vs baseline: 1.7533x; 1.5779x over previous
//
#include <hip/hip_runtime.h>

typedef __attribute__((ext_vector_type(8)))  short short8;
typedef __attribute__((ext_vector_type(16))) float f32x16;
typedef __attribute__((ext_vector_type(16))) unsigned u32x16;

#define NPTS 2048
#define BATCH 32
#define NUM_CLASSES 6
#define THREADS 512
// grid = 2 dirs * 32 batches * 4 qchunks(512) = 256 blocks (1 block/CU)
#define BF16_ONE ((short)0x3F80)
#define FMAX_BITS 0x7F7FFFFFu

__device__ __forceinline__ unsigned short f2bf(float x) {
    union { float f; unsigned u; } v; v.f = x;
    unsigned r = v.u + 0x7FFF + ((v.u >> 16) & 1);   // RNE to bf16
    return (unsigned short)(r >> 16);
}
__device__ __forceinline__ float bf2f(unsigned short h) {
    union { unsigned u; float f; } v; v.u = ((unsigned)h) << 16; return v.f;
}
__device__ __forceinline__ unsigned f2u(float x) {
    union { float f; unsigned u; } v; v.f = x; return v.u;
}
__device__ __forceinline__ float u2f(unsigned x) {
    union { unsigned u; float f; } v; v.u = x; return v.f;
}
// Distances strictly positive -> uint order == float order (R15-verified).
__device__ __forceinline__ unsigned umin2(unsigned a, unsigned b) {
    return a < b ? a : b;
}
template<int CTRL>
__device__ __forceinline__ unsigned dpp_ror_umin(unsigned v) {
    unsigned r = (unsigned)__builtin_amdgcn_update_dpp((int)v, (int)v, CTRL, 0xF, 0xF, false);
    return umin2(v, r);
}
__device__ __forceinline__ unsigned swz16_umin(unsigned v) {
    unsigned r = (unsigned)__builtin_amdgcn_ds_swizzle((int)v, 0x401F);  // lane^16
    return umin2(v, r);
}

// K-slot plan (K=16), D = a2 + b2 - 2 a.b (absmax-0 verified R3-R21):
//  k0-2: A=ah B=-2bh | k3-5: A=al B=-2bh | k6-8: A=ah B=-2bl
//  k9: A=1 B=b2h | k10: A=1 B=b2l | k11: A=a2h B=1 | k12: A=a2l B=1 | k13-15: 0
// LDS: per 32-cand tile, 1024 B = [32 x kg0][32 x kg1], conflict-free (R13).
// __launch_bounds__(512,2): 8 waves/block, 1 block/CU, 2 waves/SIMD at the
// 256-VGPR budget (R15-proven register mode). vs R19's 256-thr blocks: each
// (dir,batch) staged by 4 blocks not 8 -> conversion/thread and raw-input
// refetch both halve; loop identical. (R21 lesson: staging BYTES cost, not
// staging ALU -- so convert in-kernel from the 12B/cand raw points.)
__global__ __launch_bounds__(THREADS, 2) void chamfer_mfma32(
    const float* __restrict__ inst, const float* __restrict__ model,
    float* __restrict__ partial)
{
    __shared__ char  cands[NPTS * 32];   // 64 KB
    __shared__ float wsum[8];

    const int blk   = blockIdx.x;
    const int dir   = blk >> 7;
    const int batch = (blk >> 2) & 31;
    const int qc    = blk & 3;
    const int tid   = threadIdx.x;
    const int lane  = tid & 63, wid = tid >> 6;     // wid 0..7
    const int lh    = lane >> 5, lr = lane & 31;

    const float* __restrict__ Q = dir ? model : inst;
    const float* __restrict__ C = dir ? inst  : model;

    // ---- stage candidates into tiled B-frag layout (4 cands/thread) ----
    const float* cb = C + (size_t)batch * NPTS * 3;
    for (int c = tid; c < NPTS; c += THREADS) {
        float bx = cb[c*3+0], by = cb[c*3+1], bz = cb[c*3+2];
        float m2x = -2.f*bx, m2y = -2.f*by, m2z = -2.f*bz;
        unsigned short hx = f2bf(m2x), hy = f2bf(m2y), hz = f2bf(m2z);
        unsigned short lx = f2bf(m2x - bf2f(hx));
        unsigned short ly = f2bf(m2y - bf2f(hy));
        unsigned short lz = f2bf(m2z - bf2f(hz));
        float b2 = fmaf(bx,bx, fmaf(by,by, bz*bz));
        unsigned short b2h = f2bf(b2);
        unsigned short b2l = f2bf(b2 - bf2f(b2h));
        short8 kg0 = { (short)hx,(short)hy,(short)hz,(short)hx,(short)hy,(short)hz,(short)lx,(short)ly };
        short8 kg1 = { (short)lz,(short)b2h,(short)b2l, BF16_ONE, BF16_ONE, 0,0,0 };
        char* tbase = cands + (c >> 5) * 1024 + (c & 31) * 16;
        *(short8*)(tbase)       = kg0;
        *(short8*)(tbase + 512) = kg1;
    }

    // ---- A-frags from global (row = lane&31, k = (lane>>5)*8 + j) ----
    short8 af0, af1;
    const float* qb = Q + ((size_t)batch * NPTS + (size_t)qc * 512) * 3;
    #pragma unroll
    for (int qt = 0; qt < 2; ++qt) {
        const int qi = (wid * 2 + qt) * 32 + lr;    // 0..511
        float x = qb[qi*3+0], y = qb[qi*3+1], z = qb[qi*3+2];
        unsigned short hx = f2bf(x), hy = f2bf(y), hz = f2bf(z);
        unsigned short lx = f2bf(x - bf2f(hx));
        unsigned short ly = f2bf(y - bf2f(hy));
        unsigned short lz = f2bf(z - bf2f(hz));
        float a2 = fmaf(x,x, fmaf(y,y, z*z));
        unsigned short a2h = f2bf(a2);
        unsigned short a2l = f2bf(a2 - bf2f(a2h));
        short8 f;
        if (lh == 0)
            f = (short8){ (short)hx,(short)hy,(short)hz,(short)lx,(short)ly,(short)lz,(short)hx,(short)hy };
        else
            f = (short8){ (short)hz, BF16_ONE, BF16_ONE, (short)a2h,(short)a2l, 0,0,0 };
        if (qt == 0) af0 = f; else af1 = f;
    }
    __syncthreads();

    // ---- software-pipelined main loop: 32 stages of 2 tiles (R18-verified) ----
    u32x16 mnU, mnU2;
    f32x16 zero16;
    #pragma unroll
    for (int r = 0; r < 16; ++r) { mnU[r] = FMAX_BITS; mnU2[r] = FMAX_BITS; zero16[r] = 0.f; }

    const char* cp = cands + lh * 512 + lr * 16;
    short8 c0 = *(const short8*)(cp);
    short8 c1 = *(const short8*)(cp + 1024);
    short8 n0 = *(const short8*)(cp + 2048);
    short8 n1 = *(const short8*)(cp + 3072);
    cp += 4096;
    f32x16 p00 = __builtin_amdgcn_mfma_f32_32x32x16_bf16(af0, c0, zero16, 0,0,0);
    f32x16 p01 = __builtin_amdgcn_mfma_f32_32x32x16_bf16(af0, c1, zero16, 0,0,0);
    f32x16 p10 = __builtin_amdgcn_mfma_f32_32x32x16_bf16(af1, c0, zero16, 0,0,0);
    f32x16 p11 = __builtin_amdgcn_mfma_f32_32x32x16_bf16(af1, c1, zero16, 0,0,0);

    #pragma unroll 2
    for (int s = 1; s < 31; ++s) {        // stages 1..30 (tiles 2..61)
        c0 = n0; c1 = n1;
        n0 = *(const short8*)(cp);        // prefetch stage s+1
        n1 = *(const short8*)(cp + 1024);
        cp += 2048;
        f32x16 q00 = __builtin_amdgcn_mfma_f32_32x32x16_bf16(af0, c0, zero16, 0,0,0);
        f32x16 q01 = __builtin_amdgcn_mfma_f32_32x32x16_bf16(af0, c1, zero16, 0,0,0);
        f32x16 q10 = __builtin_amdgcn_mfma_f32_32x32x16_bf16(af1, c0, zero16, 0,0,0);
        f32x16 q11 = __builtin_amdgcn_mfma_f32_32x32x16_bf16(af1, c1, zero16, 0,0,0);
        #pragma unroll
        for (int r = 0; r < 16; ++r)      // fold stage s-1 (completed)
            mnU[r]  = umin2(umin2(f2u(p00[r]), f2u(p01[r])), mnU[r]);
        #pragma unroll
        for (int r = 0; r < 16; ++r)
            mnU2[r] = umin2(umin2(f2u(p10[r]), f2u(p11[r])), mnU2[r]);
        p00 = q00; p01 = q01; p10 = q10; p11 = q11;
    }
    {   // stage 31 (tiles 62,63, prefetched in n0/n1) + drain folds
        f32x16 q00 = __builtin_amdgcn_mfma_f32_32x32x16_bf16(af0, n0, zero16, 0,0,0);
        f32x16 q01 = __builtin_amdgcn_mfma_f32_32x32x16_bf16(af0, n1, zero16, 0,0,0);
        f32x16 q10 = __builtin_amdgcn_mfma_f32_32x32x16_bf16(af1, n0, zero16, 0,0,0);
        f32x16 q11 = __builtin_amdgcn_mfma_f32_32x32x16_bf16(af1, n1, zero16, 0,0,0);
        #pragma unroll
        for (int r = 0; r < 16; ++r) {
            mnU[r]  = umin2(umin2(f2u(p00[r]), f2u(p01[r])), mnU[r]);
            mnU2[r] = umin2(umin2(f2u(p10[r]), f2u(p11[r])), mnU2[r]);
        }
        #pragma unroll
        for (int r = 0; r < 16; ++r) {
            mnU[r]  = umin2(umin2(f2u(q00[r]), f2u(q01[r])), mnU[r]);
            mnU2[r] = umin2(umin2(f2u(q10[r]), f2u(q11[r])), mnU2[r]);
        }
    }

    // ---- epilogue: DPP row_ror col-reduce (R19-verified) ----
    float s = 0.f;
    #pragma unroll
    for (int r = 0; r < 16; ++r) {
        unsigned v = mnU[r];
        v = dpp_ror_umin<0x121>(v);
        v = dpp_ror_umin<0x122>(v);
        v = dpp_ror_umin<0x124>(v);
        v = dpp_ror_umin<0x128>(v);
        v = swz16_umin(v);
        s += u2f(v);
        unsigned w = mnU2[r];
        w = dpp_ror_umin<0x121>(w);
        w = dpp_ror_umin<0x122>(w);
        w = dpp_ror_umin<0x124>(w);
        w = dpp_ror_umin<0x128>(w);
        w = swz16_umin(w);
        s += u2f(w);
    }
    s += __shfl_xor(s, 32, 64);      // combine lh=0 / lh=1 query halves
    if (lane == 0) wsum[wid] = s;
    __syncthreads();
    if (tid == 0) {
        float t = ((wsum[0] + wsum[1]) + (wsum[2] + wsum[3]))
                + ((wsum[4] + wsum[5]) + (wsum[6] + wsum[7]));
        partial[blk] = t;
    }
}

__global__ __launch_bounds__(256) void finalize_kernel(
    const float* __restrict__ partial, const float* __restrict__ pred,
    const int* __restrict__ gt, float* __restrict__ out)
{
    __shared__ float s_ce[BATCH];
    __shared__ float wsum[4];
    const int tid = threadIdx.x;

    float v = partial[tid];          // 256 partials
    #pragma unroll
    for (int o = 32; o > 0; o >>= 1) v += __shfl_down(v, o, 64);
    const int lane = tid & 63, wid = tid >> 6;
    if (lane == 0) wsum[wid] = v;

    if (tid < BATCH) {
        const float* row = pred + tid * NUM_CLASSES;
        float mx = row[0];
        #pragma unroll
        for (int c = 1; c < NUM_CLASSES; ++c) mx = fmaxf(mx, row[c]);
        float se = 0.f;
        #pragma unroll
        for (int c = 0; c < NUM_CLASSES; ++c) se += __expf(row[c] - mx);
        const int lbl = gt[tid];
        s_ce[tid] = -(row[lbl] - mx - __logf(se));
    }
    __syncthreads();

    if (tid == 0) {
        float cd_sum = (wsum[0] + wsum[1]) + (wsum[2] + wsum[3]);
        float cd = cd_sum / (float)(BATCH * NPTS);
        float ce = 0.f;
        for (int i = 0; i < BATCH; ++i) ce += s_ce[i];
        ce /= (float)BATCH;
        out[0] = 5.f * cd + ce;
        out[1] = cd;
        out[2] = ce;
    }
}

extern "C" void kernel_launch(void* const* d_in, const int* in_sizes, int n_in,
                              void* d_out, int out_size, void* d_ws, size_t ws_size,
                              hipStream_t stream) {
    const float* inst  = (const float*)d_in[0];
    const float* model = (const float*)d_in[1];
    const float* pred  = (const float*)d_in[2];
    const int*   gt    = (const int*)d_in[3];
    float* out     = (float*)d_out;
    float* partial = (float*)d_ws;   // 256 floats

    chamfer_mfma32<<<256, THREADS, 0, stream>>>(inst, model, partial);
    finalize_kernel<<<1, 256, 0, stream>>>(partial, pred, gt, out);
}